// Round 4
// baseline (429.981 us; speedup 1.0000x reference)
//
#include <hip/hip_runtime.h>
#include <hip/hip_bf16.h>

// ConvAttention: 4x [conv(1,5)+BN+LReLU(0.3)] -> per-(b,c) attention over W with
// softmax over last axis, + pe residual.  B=16 Cin=32 Cout=64 H=16 W=512.
// Inputs are fp32 per the reference (runtime-discriminated vs bf16 via var_q's
// first word, as belt-and-braces).  OUTPUT IS fp32 (reference output dtype).
// Internals: q/k/v/pe in bf16 (MFMA), fp32 accumulation throughout.

typedef __attribute__((ext_vector_type(8))) short short8;   // 8 x bf16 (4 VGPR)
typedef __attribute__((ext_vector_type(4))) float floatx4;  // MFMA acc

#define Q_ELEMS 8388608u     // 16*64*16*512 elements per tensor (q/k/v)

__device__ __forceinline__ float bf2f(unsigned short u) {
    union { unsigned int i; float f; } c; c.i = ((unsigned int)u) << 16; return c.f;
}
__device__ __forceinline__ unsigned short f2bf(float f) {   // RNE
    union { unsigned int i; float f; } c; c.f = f;
    unsigned int r = c.i + 0x7FFFu + ((c.i >> 16) & 1u);
    return (unsigned short)(r >> 16);
}

struct AllIn { const void* p[21]; };

// ---------------------------------------------------------------------------
// Conv kernel: one block per (b, h, sel). im2col GEMM, M=co(64) N=w(512) K=160.
// K-order k = t*32 + ci  =>  K-step kk has fixed tap t=kk, ci = quad*8+j, so
// B-fragments are contiguous ds_read_b128 from the transposed x slice.
// q/k/v (sel<3) -> ws as bf16.  pe (sel==3) -> d_out as fp32 (attn adds later).
// ---------------------------------------------------------------------------
__global__ __launch_bounds__(256) void conv_kernel(AllIn in,
                                                   unsigned short* __restrict__ ws_qkv,
                                                   float* __restrict__ outg)
{
    __shared__ unsigned short xt[516][40];    // xt[w+2][ci]; rows 80B (16B-aligned b128)
    __shared__ unsigned short wl[64][168];    // wl[co][t*32+ci]; rows 336B

    const bool isbf = (*(const unsigned int*)in.p[5] == 0x3F803F80u);

    const int tid = threadIdx.x;
    const int blk = blockIdx.x;               // 1024 = 16b * 16h * 4sel
    const int sel = blk & 3, h = (blk >> 2) & 15, b = blk >> 6;

    // ---- load x[b,:,h,:] transposed into LDS, converting dtype (halo=2, zeroed) ----
    for (int it = 0; it < 8; ++it) {
        int c = it * 256 + tid;               // 2048 chunks of 8 elems
        int ci = c >> 6;
        int w8 = (c & 63) << 3;
        const size_t row = (((size_t)(b * 32 + ci) * 16 + h) << 9) + w8;
        unsigned short e[8];
        if (isbf) {
            const uint4 d = *(const uint4*)((const unsigned short*)in.p[0] + row);
            const unsigned short* p = (const unsigned short*)&d;
            #pragma unroll
            for (int j = 0; j < 8; ++j) e[j] = p[j];
        } else {
            const float* xf = (const float*)in.p[0] + row;
            const float4 a = *(const float4*)xf;
            const float4 d = *(const float4*)(xf + 4);
            e[0] = f2bf(a.x); e[1] = f2bf(a.y); e[2] = f2bf(a.z); e[3] = f2bf(a.w);
            e[4] = f2bf(d.x); e[5] = f2bf(d.y); e[6] = f2bf(d.z); e[7] = f2bf(d.w);
        }
        #pragma unroll
        for (int j = 0; j < 8; ++j) xt[w8 + j + 2][ci] = e[j];
    }
    if (tid < 128) {                          // zero halo rows 0,1,514,515
        const int rows0 = (tid >> 5);
        const int rr = (rows0 < 2) ? rows0 : (512 + rows0);
        xt[rr][tid & 31] = 0;
    }
    // ---- load weights permuted+converted: wl[co][t*32+ci] = w[co][ci][t] ----
    {
        const void* wp = in.p[1 + 5 * sel];
        for (int i = tid; i < 10240; i += 256) {
            int co = i / 160;
            int r  = i - co * 160;
            int ci = r / 5;
            int t  = r - ci * 5;
            unsigned short wv_ = isbf ? ((const unsigned short*)wp)[i]
                                      : f2bf(((const float*)wp)[i]);
            wl[co][t * 32 + ci] = wv_;
        }
    }
    __syncthreads();

    const int lane = tid & 63, wv = tid >> 6;
    const int n = lane & 15, quad = lane >> 4;
    const int co0 = wv * 16;                  // wave's M-tile

    // A frags (weights), k = kk*32 + quad*8 + j
    short8 afrag[5];
    #pragma unroll
    for (int kk = 0; kk < 5; ++kk)
        afrag[kk] = *(const short8*)&wl[co0 + n][kk * 32 + quad * 8];

    // BN constants for this lane's 4 output rows (D rows = quad*4+r)
    float sc[4], sh[4];
    #pragma unroll
    for (int r = 0; r < 4; ++r) {
        int co = co0 + quad * 4 + r;
        const void* gp = in.p[2 + 5 * sel];
        const void* bp = in.p[3 + 5 * sel];
        const void* mp = in.p[4 + 5 * sel];
        const void* vp = in.p[5 + 5 * sel];
        float gg = isbf ? bf2f(((const unsigned short*)gp)[co]) : ((const float*)gp)[co];
        float bb = isbf ? bf2f(((const unsigned short*)bp)[co]) : ((const float*)bp)[co];
        float mm = isbf ? bf2f(((const unsigned short*)mp)[co]) : ((const float*)mp)[co];
        float vv = isbf ? bf2f(((const unsigned short*)vp)[co]) : ((const float*)vp)[co];
        sc[r] = gg * rsqrtf(vv + 1e-5f);
        sh[r] = bb - mm * sc[r];
    }

    unsigned short* outq = ws_qkv + (size_t)sel * Q_ELEMS;   // sel<3 only
    for (int nt = 0; nt < 32; ++nt) {
        const int w0 = nt * 16;
        floatx4 acc = {0.f, 0.f, 0.f, 0.f};
        #pragma unroll
        for (int kk = 0; kk < 5; ++kk) {
            // B[k=t*32+ci][n=w] = x[ci][w0+n + kk - 2]  (xt has +2 offset)
            short8 bfrag = *(const short8*)&xt[w0 + n + kk][quad * 8];
            acc = __builtin_amdgcn_mfma_f32_16x16x32_bf16(afrag[kk], bfrag, acc, 0, 0, 0);
        }
        #pragma unroll
        for (int r = 0; r < 4; ++r) {
            int co = co0 + quad * 4 + r;
            float y = acc[r] * sc[r] + sh[r];
            y = (y >= 0.f) ? y : 0.3f * y;                 // LeakyReLU(0.3)
            const size_t o = (((size_t)(b * 64 + co) * 16 + h) << 9) + w0 + n;
            if (sel < 3) outq[o] = f2bf(y);
            else         outg[o] = y;                      // pe, fp32, staged in d_out
        }
    }
}

// ---------------------------------------------------------------------------
// Attention kernel: one block (4 waves) per (b,c) pair.
//   pass A: l[w] = sum_v exp(S[w,v]); S = Q^T K, K-dim = h (16, zero-padded to 32)
//   pass B: out[h,v] = sum_w V[h,w] * exp(S[w,v]) / l[w]  + pe[h,v]
// |S| <~ 7 analytically; S clamped to [-80,80] and sum floored as NaN guards.
// peg aliases outg (pe staged in d_out, fp32): each element is read then written
// by the same thread, and (b,c) ranges are block-disjoint -> race-free.
// ---------------------------------------------------------------------------
__global__ __launch_bounds__(256) void attn_kernel(const unsigned short* __restrict__ qg,
                                                   const unsigned short* __restrict__ kg,
                                                   const unsigned short* __restrict__ vg,
                                                   const float* __restrict__ peg,
                                                   float* __restrict__ outg)
{
    __shared__ unsigned short qT[512][16];     // qT[w][h]
    __shared__ unsigned short kT[512][16];     // kT[v][h]
    __shared__ unsigned short vl[16][520];     // vl[h][w] (row pad: 1040B, 16B-aligned)
    __shared__ float rcpl[512];                // 1 / l[w]
    __shared__ unsigned int Pt[4][16][20];     // per-wave P' tile [v][w-local 32 bf16]

    const int tid = threadIdx.x;
    const int bc = blockIdx.x;                 // 1024 = (b*64 + c)
    const size_t base = (size_t)bc << 13;      // *8192 elems

    // ---- load q,k transposed; v natural ----
    for (int it = 0; it < 4; ++it) {
        int c = it * 256 + tid;                // 1024 chunks of 8
        int h = c >> 6, w8 = (c & 63) << 3;
        uint4 dq = *(const uint4*)(qg + base + (h << 9) + w8);
        uint4 dk = *(const uint4*)(kg + base + (h << 9) + w8);
        uint4 dv = *(const uint4*)(vg + base + (h << 9) + w8);
        const unsigned short* pq = (const unsigned short*)&dq;
        const unsigned short* pk = (const unsigned short*)&dk;
        #pragma unroll
        for (int j = 0; j < 8; ++j) {
            qT[w8 + j][h] = pq[j];
            kT[w8 + j][h] = pk[j];
        }
        *(uint4*)&vl[h][w8] = dv;
    }
    __syncthreads();

    const int lane = tid & 63, wv = tid >> 6;
    const int n = lane & 15, quad = lane >> 4;
    const short8 z8 = {0, 0, 0, 0, 0, 0, 0, 0};
    const floatx4 zf = {0.f, 0.f, 0.f, 0.f};

    // ---- pass A: softmax denominators ----
    for (int s = 0; s < 8; ++s) {
        const int w0 = (wv * 8 + s) * 16;      // wave's w-tile
        short8 aq = (quad < 2) ? *(const short8*)&qT[w0 + n][quad * 8] : z8;  // k=h pad
        float sum[4] = {0.f, 0.f, 0.f, 0.f};
        for (int vt = 0; vt < 32; ++vt) {
            short8 bk = (quad < 2) ? *(const short8*)&kT[vt * 16 + n][quad * 8] : z8;
            floatx4 d = __builtin_amdgcn_mfma_f32_16x16x32_bf16(aq, bk, zf, 0, 0, 0);
            #pragma unroll
            for (int r = 0; r < 4; ++r)
                sum[r] += __expf(fmaxf(fminf(d[r], 80.f), -80.f));
        }
        #pragma unroll
        for (int off = 1; off < 16; off <<= 1) {
            #pragma unroll
            for (int r = 0; r < 4; ++r) sum[r] += __shfl_xor(sum[r], off, 64);
        }
        if (n == 0) {
            #pragma unroll
            for (int r = 0; r < 4; ++r)
                rcpl[w0 + quad * 4 + r] = 1.0f / fmaxf(sum[r], 1e-30f);
        }
    }
    __syncthreads();

    // ---- pass B: out accumulation; wave owns v-range [wv*128, wv*128+128) ----
    const int v0 = wv * 128;
    short8 bk[8];
    #pragma unroll
    for (int nt = 0; nt < 8; ++nt)
        bk[nt] = (quad < 2) ? *(const short8*)&kT[v0 + nt * 16 + n][quad * 8] : z8;

    floatx4 acc[8];
    #pragma unroll
    for (int nt = 0; nt < 8; ++nt) acc[nt] = zf;

    for (int kc = 0; kc < 16; ++kc) {          // w-chunks of 32 (contraction)
        const int w0 = kc * 32;
        short8 aq0 = (quad < 2) ? *(const short8*)&qT[w0 + n][quad * 8] : z8;
        short8 aq1 = (quad < 2) ? *(const short8*)&qT[w0 + 16 + n][quad * 8] : z8;
        short8 av  = *(const short8*)&vl[n][w0 + quad * 8];   // A: m=h, k=w
        float rl0[4], rl1[4];
        #pragma unroll
        for (int r = 0; r < 4; ++r) {
            rl0[r] = rcpl[w0 + quad * 4 + r];
            rl1[r] = rcpl[w0 + 16 + quad * 4 + r];
        }
        #pragma unroll
        for (int nt = 0; nt < 8; ++nt) {
            floatx4 s0 = __builtin_amdgcn_mfma_f32_16x16x32_bf16(aq0, bk[nt], zf, 0, 0, 0);
            floatx4 s1 = __builtin_amdgcn_mfma_f32_16x16x32_bf16(aq1, bk[nt], zf, 0, 0, 0);
            // P' = exp(clamp(S))/l[w], bf16-packed, via per-wave LDS tile
            // (MFMA C-layout -> B-operand layout; DS in-order per wave,
            //  asm memory clobbers pin compiler ordering)
            #define EXPC(v, rl) (__expf(fmaxf(fminf((v), 80.f), -80.f)) * (rl))
            unsigned int u00 = (unsigned int)f2bf(EXPC(s0[0], rl0[0]))
                             | ((unsigned int)f2bf(EXPC(s0[1], rl0[1])) << 16);
            unsigned int u01 = (unsigned int)f2bf(EXPC(s0[2], rl0[2]))
                             | ((unsigned int)f2bf(EXPC(s0[3], rl0[3])) << 16);
            unsigned int u10 = (unsigned int)f2bf(EXPC(s1[0], rl1[0]))
                             | ((unsigned int)f2bf(EXPC(s1[1], rl1[1])) << 16);
            unsigned int u11 = (unsigned int)f2bf(EXPC(s1[2], rl1[2]))
                             | ((unsigned int)f2bf(EXPC(s1[3], rl1[3])) << 16);
            #undef EXPC
            Pt[wv][n][quad * 2]         = u00;   // w-local quad*4 + 0..1
            Pt[wv][n][quad * 2 + 1]     = u01;   // w-local quad*4 + 2..3
            Pt[wv][n][8 + quad * 2]     = u10;   // w-local 16+quad*4 + 0..1
            Pt[wv][n][8 + quad * 2 + 1] = u11;   // w-local 16+quad*4 + 2..3
            __asm__ volatile("" ::: "memory");   // no load hoisting past stores
            union { uint4 u; short8 s; } bpc;
            bpc.u = *(const uint4*)&Pt[wv][n][quad * 4];  // B: k=w-local, n=v
            __asm__ volatile("" ::: "memory");
            acc[nt] = __builtin_amdgcn_mfma_f32_16x16x32_bf16(av, bpc.s, acc[nt], 0, 0, 0);
        }
    }

    // ---- epilogue: + pe, store fp32 ----
    #pragma unroll
    for (int nt = 0; nt < 8; ++nt) {
        #pragma unroll
        for (int r = 0; r < 4; ++r) {
            const int hrow = quad * 4 + r;
            const size_t o = base + ((size_t)hrow << 9) + (v0 + nt * 16 + n);
            outg[o] = acc[nt][r] + peg[o];
        }
    }
}

// ---------------------------------------------------------------------------
extern "C" void kernel_launch(void* const* d_in, const int* in_sizes, int n_in,
                              void* d_out, int out_size, void* d_ws, size_t ws_size,
                              hipStream_t stream)
{
    AllIn ai;
    for (int i = 0; i < 21; ++i) ai.p[i] = d_in[i];

    unsigned short* ws  = (unsigned short*)d_ws;   // q,k,v bf16: 50.3 MiB
    float* out = (float*)d_out;                    // fp32 output (+ pe staging)

    conv_kernel<<<1024, 256, 0, stream>>>(ai, ws, out);
    attn_kernel<<<1024, 256, 0, stream>>>(ws,
                                          ws + (size_t)Q_ELEMS,
                                          ws + 2 * (size_t)Q_ELEMS,
                                          out,            // pe (aliases out)
                                          out);
}

// Round 6
// 294.554 us; speedup vs baseline: 1.4598x; 1.4598x over previous
//
#include <hip/hip_runtime.h>
#include <hip/hip_bf16.h>

// ConvAttention: 4x [conv(1,5)+BN+LReLU(0.3)] -> per-(b,c) attention over W with
// softmax over last axis, + pe residual.  B=16 Cin=32 Cout=64 H=16 W=512.
// fp32 in / fp32 out (verified R4).  Internals bf16 MFMA, fp32 accumulation.
// R6: d_out is WRITE-ONLY (single writer: attn). q/k/v/pe all staged bf16 in
// ws (4 x 16.78 MB = exactly 64 MiB).  No buffer is both read+written by any
// kernel -> no initial-state/aliasing/poison dependence (fixes R5 replay bug).

typedef __attribute__((ext_vector_type(8))) short short8;   // 8 x bf16 (4 VGPR)
typedef __attribute__((ext_vector_type(4))) float floatx4;  // MFMA acc

#define Q_ELEMS 8388608u     // 16*64*16*512 elements per tensor (q/k/v/pe)
#define LOG2E   1.44269504088896340736f

__device__ __forceinline__ float bf2f(unsigned short u) {
    union { unsigned int i; float f; } c; c.i = ((unsigned int)u) << 16; return c.f;
}
__device__ __forceinline__ unsigned short f2bf(float f) {   // RNE
    union { unsigned int i; float f; } c; c.f = f;
    unsigned int r = c.i + 0x7FFFu + ((c.i >> 16) & 1u);
    return (unsigned short)(r >> 16);
}
__device__ __forceinline__ unsigned int pkbf(float lo, float hi) {  // bf16(hi)<<16|bf16(lo)
    __hip_bfloat162 h2 = __float22bfloat162_rn(make_float2(lo, hi));
    union { __hip_bfloat162 h; unsigned int u; } c; c.h = h2; return c.u;
}

struct AllIn { const void* p[21]; };

// ---------------------------------------------------------------------------
// Conv kernel: one block per (b, h, sel). im2col GEMM, M=co(64) N=w(512) K=160.
// K-order k = t*32 + ci  =>  K-step kk has fixed tap t=kk, ci = quad*8+j.
// Weights read straight from global into A-frags (no LDS).  Epilogue for ALL
// sel goes through a per-wave LDS tile -> coalesced uint4 bf16 stores to ws.
// sel==0 (q) output pre-scaled by log2(e) (LReLU commutes with positive scale).
// ---------------------------------------------------------------------------
__global__ __launch_bounds__(256, 3) void conv_kernel(AllIn in,
                                                      unsigned short* __restrict__ ws_out)
{
    __shared__ unsigned short xt[516][40];    // xt[w+2][ci]; rows 80B, 41.3 KB
    __shared__ unsigned short Dt[4][16][40];  // per-wave C tile [co16][w32+pad], 5.1 KB

    const bool isbf = (*(const unsigned int*)in.p[5] == 0x3F803F80u);

    const int tid = threadIdx.x;
    const int blk = blockIdx.x;               // 1024 = 16b * 16h * 4sel
    const int sel = blk & 3, h = (blk >> 2) & 15, b = blk >> 6;

    // ---- stage x[b,:,h,:] transposed, stride-1 lane mapping ----
    {
        const int lw = tid & 63;              // lane w-base
        const int cg = tid >> 6;              // ci group 0..3
        for (int it = 0; it < 8; ++it) {
            const int ci = it * 4 + cg;
            const size_t row = ((size_t)(b * 32 + ci) * 16 + h) << 9;
            #pragma unroll
            for (int m = 0; m < 8; ++m) {
                const int w = lw + 64 * m;
                unsigned short e = isbf ? ((const unsigned short*)in.p[0])[row + w]
                                        : f2bf(((const float*)in.p[0])[row + w]);
                xt[w + 2][ci] = e;
            }
        }
    }
    if (tid < 128) {                          // zero halo rows 0,1,514,515
        const int rows0 = (tid >> 5);
        const int rr = (rows0 < 2) ? rows0 : (512 + rows0);
        xt[rr][tid & 31] = 0;
    }
    __syncthreads();

    const int lane = tid & 63, wv = tid >> 6;
    const int n = lane & 15, quad = lane >> 4;
    const int co0 = wv * 16;                  // wave's M-tile

    // ---- A frags (weights) straight from global: k = kk*32 + quad*8 + j ----
    short8 afrag[5];
    {
        const void* wp = in.p[1 + 5 * sel];
        #pragma unroll
        for (int kk = 0; kk < 5; ++kk) {
            short8 a;
            #pragma unroll
            for (int j = 0; j < 8; ++j) {
                const int idx = (co0 + n) * 160 + (quad * 8 + j) * 5 + kk;
                a[j] = (short)(isbf ? ((const unsigned short*)wp)[idx]
                                    : f2bf(((const float*)wp)[idx]));
            }
            afrag[kk] = a;
        }
    }

    // ---- BN constants (D rows = quad*4+r); q gets the log2e fold ----
    float sc[4], sh[4];
    #pragma unroll
    for (int r = 0; r < 4; ++r) {
        const int co = co0 + quad * 4 + r;
        const void* gp = in.p[2 + 5 * sel];
        const void* bp = in.p[3 + 5 * sel];
        const void* mp = in.p[4 + 5 * sel];
        const void* vp = in.p[5 + 5 * sel];
        float gg = isbf ? bf2f(((const unsigned short*)gp)[co]) : ((const float*)gp)[co];
        float bb = isbf ? bf2f(((const unsigned short*)bp)[co]) : ((const float*)bp)[co];
        float mm = isbf ? bf2f(((const unsigned short*)mp)[co]) : ((const float*)mp)[co];
        float vv = isbf ? bf2f(((const unsigned short*)vp)[co]) : ((const float*)vp)[co];
        sc[r] = gg * rsqrtf(vv + 1e-5f);
        sh[r] = bb - mm * sc[r];
        if (sel == 0) { sc[r] *= LOG2E; sh[r] *= LOG2E; }   // LReLU-commutable
    }

    unsigned short* outq = ws_out + (size_t)sel * Q_ELEMS;
    for (int nt2 = 0; nt2 < 16; ++nt2) {      // 32-w groups
        const int w0g = nt2 * 32;
        #pragma unroll
        for (int half = 0; half < 2; ++half) {
            const int w0 = w0g + half * 16;
            floatx4 acc = {0.f, 0.f, 0.f, 0.f};
            #pragma unroll
            for (int kk = 0; kk < 5; ++kk) {
                short8 bfrag = *(const short8*)&xt[w0 + n + kk][quad * 8];
                acc = __builtin_amdgcn_mfma_f32_16x16x32_bf16(afrag[kk], bfrag, acc, 0, 0, 0);
            }
            #pragma unroll
            for (int r = 0; r < 4; ++r) {
                float y = acc[r] * sc[r] + sh[r];
                y = fmaxf(y, 0.3f * y);                       // LeakyReLU(0.3)
                Dt[wv][quad * 4 + r][half * 16 + n] = f2bf(y);
            }
        }
        // per-wave roundtrip -> coalesced bf16 uint4 stores (all sel)
        __asm__ volatile("" ::: "memory");
        const uint4 d = *(const uint4*)&Dt[wv][n][quad * 8];
        __asm__ volatile("" ::: "memory");
        *(uint4*)&outq[(((size_t)(b * 64 + co0 + n) * 16 + h) << 9) + w0g + quad * 8] = d;
    }
}

// ---------------------------------------------------------------------------
// Attention kernel: one block (4 waves) per (b,c) pair, fully resident (4/CU).
//   pass A: l[w] = sum_v exp2(S'[w,v]); S' = Q'^T K (q pre-scaled by log2e)
//   pass B: out[h,v] = sum_w (V[h,w]/l[w]) * exp2(S'[w,v])  + pe[h,v]
// V-frags are rescaled by rcpl once per kc (8 muls) instead of per element.
// pe read from ws (bf16).  d_out is write-only, each element written once.
// ---------------------------------------------------------------------------
__global__ __launch_bounds__(256, 4) void attn_kernel(const unsigned short* __restrict__ qg,
                                                      const unsigned short* __restrict__ kg,
                                                      const unsigned short* __restrict__ vg,
                                                      const unsigned short* __restrict__ peg,
                                                      float* __restrict__ outg)
{
    __shared__ unsigned short qT[512][16];     // qT[w][h]  16 KB
    __shared__ unsigned short kT[512][16];     // kT[v][h]  16 KB
    __shared__ float rcpl[512];                // 1 / l[w]   2 KB
    __shared__ unsigned int Pt[4][16][20];     // per-wave P' tile, 5.12 KB  (39.9 total)

    const int tid = threadIdx.x;
    const int bc = blockIdx.x;                 // 1024 = (b*64 + c)
    const size_t base = (size_t)bc << 13;      // *8192 elems

    const int lane = tid & 63, wv = tid >> 6;

    // ---- stage q,k transposed via in-register v_perm ----
    {
        const int wp = (wv << 7) + (lane << 1);   // wave's w-pair
        unsigned int rq[16], rk[16];
        #pragma unroll
        for (int h = 0; h < 16; ++h) {
            rq[h] = *(const unsigned int*)(qg + base + (h << 9) + wp);
            rk[h] = *(const unsigned int*)(kg + base + (h << 9) + wp);
        }
        unsigned int lo[8], hi[8];
        #pragma unroll
        for (int j = 0; j < 8; ++j) {
            lo[j] = __builtin_amdgcn_perm(rq[2 * j + 1], rq[2 * j], 0x05040100u);
            hi[j] = __builtin_amdgcn_perm(rq[2 * j + 1], rq[2 * j], 0x07060302u);
        }
        *(uint4*)&qT[wp][0]     = make_uint4(lo[0], lo[1], lo[2], lo[3]);
        *(uint4*)&qT[wp][8]     = make_uint4(lo[4], lo[5], lo[6], lo[7]);
        *(uint4*)&qT[wp + 1][0] = make_uint4(hi[0], hi[1], hi[2], hi[3]);
        *(uint4*)&qT[wp + 1][8] = make_uint4(hi[4], hi[5], hi[6], hi[7]);
        #pragma unroll
        for (int j = 0; j < 8; ++j) {
            lo[j] = __builtin_amdgcn_perm(rk[2 * j + 1], rk[2 * j], 0x05040100u);
            hi[j] = __builtin_amdgcn_perm(rk[2 * j + 1], rk[2 * j], 0x07060302u);
        }
        *(uint4*)&kT[wp][0]     = make_uint4(lo[0], lo[1], lo[2], lo[3]);
        *(uint4*)&kT[wp][8]     = make_uint4(lo[4], lo[5], lo[6], lo[7]);
        *(uint4*)&kT[wp + 1][0] = make_uint4(hi[0], hi[1], hi[2], hi[3]);
        *(uint4*)&kT[wp + 1][8] = make_uint4(hi[4], hi[5], hi[6], hi[7]);
    }
    __syncthreads();

    const int n = lane & 15, quad = lane >> 4;
    const short8 z8 = {0, 0, 0, 0, 0, 0, 0, 0};
    const floatx4 zf = {0.f, 0.f, 0.f, 0.f};

    // ---- pass A: softmax denominators ----
    for (int s = 0; s < 8; ++s) {
        const int w0 = (wv * 8 + s) * 16;
        short8 aq = (quad < 2) ? *(const short8*)&qT[w0 + n][quad * 8] : z8;  // k=h pad
        float sum[4] = {0.f, 0.f, 0.f, 0.f};
        for (int vt = 0; vt < 32; ++vt) {
            short8 bk = (quad < 2) ? *(const short8*)&kT[vt * 16 + n][quad * 8] : z8;
            floatx4 d = __builtin_amdgcn_mfma_f32_16x16x32_bf16(aq, bk, zf, 0, 0, 0);
            #pragma unroll
            for (int r = 0; r < 4; ++r) sum[r] += __builtin_amdgcn_exp2f(d[r]);
        }
        #pragma unroll
        for (int off = 1; off < 16; off <<= 1) {
            #pragma unroll
            for (int r = 0; r < 4; ++r) sum[r] += __shfl_xor(sum[r], off, 64);
        }
        if (n == 0) {
            #pragma unroll
            for (int r = 0; r < 4; ++r)
                rcpl[w0 + quad * 4 + r] = 1.0f / fmaxf(sum[r], 1e-30f);
        }
    }
    __syncthreads();

    // ---- pass B: wave owns v-range [wv*128, wv*128+128) ----
    const int v0 = wv * 128;
    short8 bk[8];
    #pragma unroll
    for (int nt = 0; nt < 8; ++nt)
        bk[nt] = (quad < 2) ? *(const short8*)&kT[v0 + nt * 16 + n][quad * 8] : z8;

    floatx4 acc[8];
    #pragma unroll
    for (int nt = 0; nt < 8; ++nt) acc[nt] = zf;

    for (int kc = 0; kc < 16; ++kc) {          // w-chunks of 32 (contraction)
        const int w0 = kc * 32;
        short8 aq0 = (quad < 2) ? *(const short8*)&qT[w0 + n][quad * 8] : z8;
        short8 aq1 = (quad < 2) ? *(const short8*)&qT[w0 + 16 + n][quad * 8] : z8;
        // av' = bf16( V[h=n][w0+quad*8+j] * rcpl[w0+quad*8+j] )  -- per-kc fold
        short8 vraw = *(const short8*)(vg + base + ((size_t)n << 9) + w0 + quad * 8);
        const float4 ra = *(const float4*)&rcpl[w0 + quad * 8];
        const float4 rb = *(const float4*)&rcpl[w0 + quad * 8 + 4];
        short8 av;
        av[0] = (short)f2bf(bf2f((unsigned short)vraw[0]) * ra.x);
        av[1] = (short)f2bf(bf2f((unsigned short)vraw[1]) * ra.y);
        av[2] = (short)f2bf(bf2f((unsigned short)vraw[2]) * ra.z);
        av[3] = (short)f2bf(bf2f((unsigned short)vraw[3]) * ra.w);
        av[4] = (short)f2bf(bf2f((unsigned short)vraw[4]) * rb.x);
        av[5] = (short)f2bf(bf2f((unsigned short)vraw[5]) * rb.y);
        av[6] = (short)f2bf(bf2f((unsigned short)vraw[6]) * rb.z);
        av[7] = (short)f2bf(bf2f((unsigned short)vraw[7]) * rb.w);

        #pragma unroll
        for (int nt = 0; nt < 8; ++nt) {
            floatx4 s0 = __builtin_amdgcn_mfma_f32_16x16x32_bf16(aq0, bk[nt], zf, 0, 0, 0);
            floatx4 s1 = __builtin_amdgcn_mfma_f32_16x16x32_bf16(aq1, bk[nt], zf, 0, 0, 0);
            // P' = exp2(S'), bf16-packed, via per-wave LDS tile (C->B layout)
            const unsigned int u00 = pkbf(__builtin_amdgcn_exp2f(s0[0]),
                                          __builtin_amdgcn_exp2f(s0[1]));
            const unsigned int u01 = pkbf(__builtin_amdgcn_exp2f(s0[2]),
                                          __builtin_amdgcn_exp2f(s0[3]));
            const unsigned int u10 = pkbf(__builtin_amdgcn_exp2f(s1[0]),
                                          __builtin_amdgcn_exp2f(s1[1]));
            const unsigned int u11 = pkbf(__builtin_amdgcn_exp2f(s1[2]),
                                          __builtin_amdgcn_exp2f(s1[3]));
            Pt[wv][n][quad * 2]         = u00;   // w-local quad*4 + 0..1
            Pt[wv][n][quad * 2 + 1]     = u01;   // w-local quad*4 + 2..3
            Pt[wv][n][8 + quad * 2]     = u10;   // w-local 16+quad*4 + 0..1
            Pt[wv][n][8 + quad * 2 + 1] = u11;   // w-local 16+quad*4 + 2..3
            __asm__ volatile("" ::: "memory");   // no load hoisting past stores
            union { uint4 u; short8 s; } bpc;
            bpc.u = *(const uint4*)&Pt[wv][n][quad * 4];  // B: k=w-local, n=v
            __asm__ volatile("" ::: "memory");
            acc[nt] = __builtin_amdgcn_mfma_f32_16x16x32_bf16(av, bpc.s, acc[nt], 0, 0, 0);
        }
    }

    // ---- epilogue: + pe (bf16 from ws), store fp32 (write-only d_out) ----
    #pragma unroll
    for (int nt = 0; nt < 8; ++nt) {
        #pragma unroll
        for (int r = 0; r < 4; ++r) {
            const int hrow = quad * 4 + r;
            const size_t o = base + ((size_t)hrow << 9) + (v0 + nt * 16 + n);
            outg[o] = acc[nt][r] + bf2f(peg[o]);
        }
    }
}

// ---------------------------------------------------------------------------
extern "C" void kernel_launch(void* const* d_in, const int* in_sizes, int n_in,
                              void* d_out, int out_size, void* d_ws, size_t ws_size,
                              hipStream_t stream)
{
    AllIn ai;
    for (int i = 0; i < 21; ++i) ai.p[i] = d_in[i];

    unsigned short* ws  = (unsigned short*)d_ws;   // q,k,v,pe bf16: exactly 64 MiB
    float* out = (float*)d_out;                    // write-only fp32 output

    conv_kernel<<<1024, 256, 0, stream>>>(ai, ws);
    attn_kernel<<<1024, 256, 0, stream>>>(ws,
                                          ws + (size_t)Q_ELEMS,
                                          ws + 2 * (size_t)Q_ELEMS,
                                          ws + 3 * (size_t)Q_ELEMS,
                                          out);
}